// Round 1
// baseline (611.108 us; speedup 1.0000x reference)
//
#include <hip/hip_runtime.h>
#include <stdint.h>

// key = (t << 32) | (pos+1); key==0 <=> empty node.
// Lexicographic u64 max == (max t, ties -> max pos).
static __device__ __forceinline__ unsigned long long pack_key(int t, int pos) {
    return ((unsigned long long)(unsigned int)t << 32) | (unsigned int)(pos + 1);
}

// Cascade thresholds. t ~ U[0, 1e6), ~Poisson(10) events/node.
// P1 unconditional (t>=T1): ~20k atomics. Each later band filter-reads the
// table (prior passes' atomics are visible across the kernel boundary) and
// only atomics when it can win: expected ~49k + ~47k + ~13k => ~130k total
// vs ~266k for the previous 2-level (750k) split.
#define T1 980000
#define T2 900000
#define T3 700000

__global__ void init_ws_kernel(unsigned long long* __restrict__ ws, int n) {
    int i = blockIdx.x * blockDim.x + threadIdx.x;
    if (i < n) ws[i] = 0ULL;
}

// P1: top band does unconditional u64 atomicMax. No pre-load filter: the
// table is all-zero at this point, a read filter can never skip anything.
__global__ void __launch_bounds__(256)
scatter_p1_kernel(const int* __restrict__ t, const int* __restrict__ idx,
                  unsigned long long* __restrict__ ws, int E) {
    int i0 = (blockIdx.x * blockDim.x + threadIdx.x) * 4;
    if (i0 + 3 < E) {
        int4 tv = *(const int4*)(t + i0);
        int4 iv = *(const int4*)(idx + i0);
        if (tv.x >= T1) atomicMax(&ws[iv.x], pack_key(tv.x, i0 + 0));
        if (tv.y >= T1) atomicMax(&ws[iv.y], pack_key(tv.y, i0 + 1));
        if (tv.z >= T1) atomicMax(&ws[iv.z], pack_key(tv.z, i0 + 2));
        if (tv.w >= T1) atomicMax(&ws[iv.w], pack_key(tv.w, i0 + 3));
    } else if (i0 < E) {
        for (int i = i0; i < E; ++i)
            if (t[i] >= T1) atomicMax(&ws[idx[i]], pack_key(t[i], i));
    }
}

// Bands 2..4: events with t in [lo, hi). The kernel boundary before each pass
// guarantees all earlier passes' atomics are visible to plain loads, so the
// filter genuinely skips events whose node already holds a higher-band max.
// Within a pass the table is monotone non-decreasing, so a stale (small) read
// only costs a redundant atomic, never a wrong skip.
__global__ void __launch_bounds__(256)
scatter_band_kernel(const int* __restrict__ t, const int* __restrict__ idx,
                    unsigned long long* __restrict__ ws, int E, int lo, int hi) {
    int i0 = (blockIdx.x * blockDim.x + threadIdx.x) * 4;
    if (i0 + 3 < E) {
        int4 tv = *(const int4*)(t + i0);
        int4 iv = *(const int4*)(idx + i0);
        if (tv.x >= lo && tv.x < hi) {
            unsigned long long k = pack_key(tv.x, i0 + 0);
            if (ws[iv.x] < k) atomicMax(&ws[iv.x], k);
        }
        if (tv.y >= lo && tv.y < hi) {
            unsigned long long k = pack_key(tv.y, i0 + 1);
            if (ws[iv.y] < k) atomicMax(&ws[iv.y], k);
        }
        if (tv.z >= lo && tv.z < hi) {
            unsigned long long k = pack_key(tv.z, i0 + 2);
            if (ws[iv.z] < k) atomicMax(&ws[iv.z], k);
        }
        if (tv.w >= lo && tv.w < hi) {
            unsigned long long k = pack_key(tv.w, i0 + 3);
            if (ws[iv.w] < k) atomicMax(&ws[iv.w], k);
        }
    } else if (i0 < E) {
        for (int i = i0; i < E; ++i) {
            if (t[i] >= lo && t[i] < hi) {
                unsigned long long k = pack_key(t[i], i);
                if (ws[idx[i]] < k) atomicMax(&ws[idx[i]], k);
            }
        }
    }
}

// Gather: 32 lanes per node (D=128 floats = 32 float4), 2 nodes per thread
// for MLP=2. Rows are 512B contiguous -> coalesced within each 32-lane group.
// (Kept byte-identical to the previous round so the dispatch breakdown stays
// attributable to the scatter change.)
__global__ void __launch_bounds__(256)
gather_kernel(const unsigned long long* __restrict__ ws,
              const float4* __restrict__ msg,
              float4* __restrict__ out, int N, int half) {
    int gid = blockIdx.x * blockDim.x + threadIdx.x;
    int lane = gid & 31;
    int na = gid >> 5;
    if (na >= half) return;
    int nb = na + half;

    unsigned long long ka = ws[na];
    unsigned long long kb = (nb < N) ? ws[nb] : 0ULL;

    float4 va = make_float4(0.f, 0.f, 0.f, 0.f);
    float4 vb = va;
    if (ka != 0ULL) {
        int pa = (int)(unsigned int)(ka & 0xFFFFFFFFULL) - 1;
        va = msg[(size_t)pa * 32 + lane];
    }
    if (kb != 0ULL) {
        int pb = (int)(unsigned int)(kb & 0xFFFFFFFFULL) - 1;
        vb = msg[(size_t)pb * 32 + lane];
    }
    out[(size_t)na * 32 + lane] = va;
    if (nb < N) out[(size_t)nb * 32 + lane] = vb;
}

extern "C" void kernel_launch(void* const* d_in, const int* in_sizes, int n_in,
                              void* d_out, int out_size, void* d_ws, size_t ws_size,
                              hipStream_t stream) {
    const float* msg = (const float*)d_in[0];
    const int* index = (const int*)d_in[1];
    const int* t     = (const int*)d_in[2];
    const int D = 128;
    const int E = in_sizes[0] / D;
    const int N = out_size / D;

    unsigned long long* ws = (unsigned long long*)d_ws;

    {
        int threads = 256;
        int blocks = (N + threads - 1) / threads;
        init_ws_kernel<<<blocks, threads, 0, stream>>>(ws, N);
    }
    {
        int threads = 256;
        int nthreads = (E + 3) / 4;
        int blocks = (nthreads + threads - 1) / threads;
        scatter_p1_kernel<<<blocks, threads, 0, stream>>>(t, index, ws, E);
        scatter_band_kernel<<<blocks, threads, 0, stream>>>(t, index, ws, E, T2, T1);
        scatter_band_kernel<<<blocks, threads, 0, stream>>>(t, index, ws, E, T3, T2);
        scatter_band_kernel<<<blocks, threads, 0, stream>>>(t, index, ws, E, 0,  T3);
    }
    {
        int threads = 256;
        int half = (N + 1) / 2;
        long long total = (long long)half * 32;
        int blocks = (int)((total + threads - 1) / threads);
        gather_kernel<<<blocks, threads, 0, stream>>>(
            ws, (const float4*)msg, (float4*)d_out, N, half);
    }
}